// Round 10
// baseline (62.699 us; speedup 1.0000x reference)
//
#include <hip/hip_runtime.h>
#include <math.h>

#define NB 8
#define N_OP 1000
#define N_MA 64
#define IN_DST 64
#define DD 128
#define NEG_SLOPE 0.2f
#define TILE_O 16
#define NTILE 64     // 64*16 = 1024 >= 1000 (tail guarded; tile 63 empty)
#define HPAD 132     // padded stride: <=2-way bank aliasing on strided LDS reduces
#define MAGIC 0x13579BDF

__device__ __forceinline__ float lrelu(float x) { return x >= 0.f ? x : NEG_SLOPE * x; }

__device__ __forceinline__ float wave_sum(float v) {
    for (int off = 32; off; off >>= 1) v += __shfl_xor(v, off, 64);
    return v;
}

struct ConsShared {
    float H[TILE_O][HPAD];     // 8.4 KB
    float ef[TILE_O][N_MA];    // 4 KB
    float ajf[TILE_O][N_MA];   // 4 KB
    float P[TILE_O][N_MA];     // 4 KB
    float u[DD];
    float el[TILE_O];
    float redz[4][64], redse[4][64];
};
struct ProdShared {
    float Wc[32][HPAD];        // 16.9 KB
    float al[DD], ar[DD];
    float v[IN_DST];
};
union ShU { ConsShared c; ProdShared p; };

// Single kernel, 520 blocks:
//  blocks [0,512): consumers — per (b, o-tile of 16): stage H + adj/ef (loads
//    issued BEFORE the spin so producer latency hides under them), spin on
//    flag[b], then el / masked-exp stats (M=0; logits bounded ~14, safe f32) /
//    partial contraction S_part.
//  blocks [512,520): producers — per b: u = W_src@attn_l (LDS-chunked,
//    coalesced), c_we, v = W_dst@attn_r, er[b,:] = h_dst[b]@v; threadfence;
//    release-store flag[b]=MAGIC. Flag persists across graph replays; inputs
//    are constant so re-written values are identical -> deterministic.
__global__ __launch_bounds__(256) void f_kernel(
    const float* __restrict__ h_src, const float* __restrict__ h_dst,
    const float* __restrict__ edge_feat, const int* __restrict__ adj,
    const float* __restrict__ W_src, const float* __restrict__ W_dst,
    const float* __restrict__ W_edge, const float* __restrict__ attn_l,
    const float* __restrict__ attn_r, float* __restrict__ S_part,
    float* __restrict__ zpart, float* __restrict__ separt,
    float* __restrict__ u_ws, float* __restrict__ cwe_ws,
    float* __restrict__ er_ws, int* __restrict__ flags) {
    __shared__ ShU sh;
    int blk = blockIdx.x;
    int t = threadIdx.x;
    int lane = t & 63, w = t >> 6;

    if (blk >= NB * NTILE) {
        // ---------------- producer for b ----------------
        int b = blk - NB * NTILE;

        // c_we (wave 0, direct coalesced global reads)
        if (w == 0) {
            float part = wave_sum(W_edge[lane] * attn_l[lane] +
                                  W_edge[lane + 64] * attn_l[lane + 64]);
            if (lane == 0) cwe_ws[0] = part;
        }
        // stage attn vectors
        if (t < DD) sh.p.al[t] = attn_l[t];
        else sh.p.ar[t - DD] = attn_r[t - DD];

        int il = t >> 3, sub = t & 7;
        // u: 4 LDS-staged chunks of 32 W_src rows (coalesced float4)
        for (int cc = 0; cc < 4; ++cc) {
            #pragma unroll
            for (int s = 0; s < 4; ++s) {
                int flat = s * 256 + t;
                int row = flat >> 5, col = (flat & 31) * 4;
                *reinterpret_cast<float4*>(&sh.p.Wc[row][col]) =
                    *reinterpret_cast<const float4*>(
                        W_src + ((size_t)(cc * 32 + row) * DD + col));
            }
            __syncthreads();
            float part = 0.f;
            #pragma unroll
            for (int q = 0; q < 16; ++q)
                part += sh.p.Wc[il][sub + 8 * q] * sh.p.al[sub + 8 * q];
            part += __shfl_xor(part, 1, 64);
            part += __shfl_xor(part, 2, 64);
            part += __shfl_xor(part, 4, 64);
            if (sub == 0) u_ws[cc * 32 + il] = part;
            __syncthreads();
        }
        // v: 2 chunks of W_dst rows
        for (int cc = 0; cc < 2; ++cc) {
            #pragma unroll
            for (int s = 0; s < 4; ++s) {
                int flat = s * 256 + t;
                int row = flat >> 5, col = (flat & 31) * 4;
                *reinterpret_cast<float4*>(&sh.p.Wc[row][col]) =
                    *reinterpret_cast<const float4*>(
                        W_dst + ((size_t)(cc * 32 + row) * DD + col));
            }
            __syncthreads();
            float part = 0.f;
            #pragma unroll
            for (int q = 0; q < 16; ++q)
                part += sh.p.Wc[il][sub + 8 * q] * sh.p.ar[sub + 8 * q];
            part += __shfl_xor(part, 1, 64);
            part += __shfl_xor(part, 2, 64);
            part += __shfl_xor(part, 4, 64);
            if (sub == 0) sh.p.v[cc * 32 + il] = part;
            __syncthreads();
        }
        // er[m] = dot(h_dst[b,m,:], v): 4 threads/m
        {
            int m = t >> 2, q4 = t & 3;
            const float* hd = h_dst + (size_t)(b * N_MA + m) * IN_DST + q4 * 16;
            float part = 0.f;
            #pragma unroll
            for (int q = 0; q < 16; ++q) part += hd[q] * sh.p.v[q4 * 16 + q];
            part += __shfl_xor(part, 1, 64);
            part += __shfl_xor(part, 2, 64);
            if (q4 == 0) er_ws[b * N_MA + m] = part;
        }
        __threadfence();
        __syncthreads();
        if (t == 0)
            __hip_atomic_store(&flags[b], MAGIC, __ATOMIC_RELEASE,
                               __HIP_MEMORY_SCOPE_AGENT);
        return;
    }

    // ---------------- consumer (b, ti) ----------------
    int b = blk >> 6, ti = blk & 63;
    int o0 = ti * TILE_O;
    int nrows = min(TILE_O, N_OP - o0);   // may be <=0 for ti==63

    // stage H tile (coalesced float4); zero OOB rows
    #pragma unroll
    for (int s = 0; s < 2; ++s) {
        int flat = s * 256 + t;            // 512 float4 slots = 16 rows x 32
        int row = flat >> 5, col = (flat & 31) * 4;
        float4 hv = make_float4(0.f, 0.f, 0.f, 0.f);
        if (row < nrows)
            hv = *reinterpret_cast<const float4*>(
                h_src + ((size_t)(b * N_OP + o0 + row) * DD + col));
        *reinterpret_cast<float4*>(&sh.c.H[row][col]) = hv;
    }
    // stage adj/ef tile (coalesced rows; zero OOB)
    #pragma unroll
    for (int s = 0; s < 4; ++s) {
        int idx = s * 256 + t;             // 1024 = 16 rows x 64 m
        int r = idx >> 6, m = idx & 63;
        float ef = 0.f, aj = 0.f;
        if (r < nrows) {
            size_t g = (size_t)(b * N_OP + o0 + r) * N_MA + m;
            ef = edge_feat[g];
            aj = adj[g] ? 1.f : 0.f;
        }
        sh.c.ef[r][m] = ef;
        sh.c.ajf[r][m] = aj;
    }

    // spin on flag[b] (producer latency hidden under the staging loads above)
    if (t == 0) {
        while (__hip_atomic_load(&flags[b], __ATOMIC_ACQUIRE,
                                 __HIP_MEMORY_SCOPE_AGENT) != MAGIC) {
            __builtin_amdgcn_s_sleep(2);
        }
    }
    __syncthreads();
    __threadfence();

    float cwe = cwe_ws[0];
    float er_bm = er_ws[b * N_MA + (t & 63)];
    if (t < DD) sh.c.u[t] = u_ws[t];
    __syncthreads();

    // el[r] = dot(H[r,:], u): 16 threads/row x 8 FMA
    {
        int r = t >> 4, sub = t & 15;
        float part = 0.f;
        #pragma unroll
        for (int q = 0; q < 8; ++q)
            part += sh.c.H[r][sub + 16 * q] * sh.c.u[sub + 16 * q];
        part += __shfl_xor(part, 1, 64);
        part += __shfl_xor(part, 2, 64);
        part += __shfl_xor(part, 4, 64);
        part += __shfl_xor(part, 8, 64);
        if (sub == 0) sh.c.el[r] = part;
    }
    __syncthreads();

    // p + per-tile stats (from LDS; M=0 exp)
    int m = t & 63, og = t >> 6;
    float z = 0.f, se = 0.f;
    #pragma unroll
    for (int r = og; r < TILE_O; r += 4) {
        float ef = sh.c.ef[r][m];
        float aj = sh.c.ajf[r][m];
        float vv = lrelu(sh.c.el[r] + er_bm + ef * cwe);
        float p = aj * __expf(vv);
        z += p;
        se += p * ef;
        sh.c.P[r][m] = p;
    }
    sh.c.redz[og][m] = z;
    sh.c.redse[og][m] = se;
    __syncthreads();

    if (t < 64) {
        zpart[ti * 512 + b * N_MA + t] =
            sh.c.redz[0][t] + sh.c.redz[1][t] + sh.c.redz[2][t] + sh.c.redz[3][t];
    } else if (t < 128) {
        int mm = t - 64;
        separt[ti * 512 + b * N_MA + mm] =
            sh.c.redse[0][mm] + sh.c.redse[1][mm] + sh.c.redse[2][mm] + sh.c.redse[3][mm];
    }

    // phase 2: S_part[m][i] = sum_k P[k][m] * H[k][i]
    int i4 = t & 31, mg = t >> 5;
    float acc[8][4];
    #pragma unroll
    for (int a = 0; a < 8; ++a)
        #pragma unroll
        for (int c = 0; c < 4; ++c) acc[a][c] = 0.f;

    #pragma unroll
    for (int k = 0; k < TILE_O; ++k) {
        float4 hv = *reinterpret_cast<const float4*>(&sh.c.H[k][i4 * 4]);
        float4 pa = *reinterpret_cast<const float4*>(&sh.c.P[k][mg * 8]);
        float4 pb = *reinterpret_cast<const float4*>(&sh.c.P[k][mg * 8 + 4]);
        float hh[4] = {hv.x, hv.y, hv.z, hv.w};
        float pp[8] = {pa.x, pa.y, pa.z, pa.w, pb.x, pb.y, pb.z, pb.w};
        #pragma unroll
        for (int mm = 0; mm < 8; ++mm)
            #pragma unroll
            for (int ii = 0; ii < 4; ++ii)
                acc[mm][ii] += pp[mm] * hh[ii];
    }

    #pragma unroll
    for (int mm = 0; mm < 8; ++mm) {
        size_t off = ((size_t)(b * NTILE + ti) * N_MA + mg * 8 + mm) * DD + i4 * 4;
        *reinterpret_cast<float4*>(S_part + off) =
            make_float4(acc[mm][0], acc[mm][1], acc[mm][2], acc[mm][3]);
    }
}

// K2: per (b,m): sum tile partials; recompute feat_dst row + er in-block;
// W_src matvec; sigmoid epilogue. (proven R9 kernel, NTILE=64)
__global__ __launch_bounds__(256) void c2_kernel(
    const float* __restrict__ S_part, const float* __restrict__ zpart,
    const float* __restrict__ separt, const float* __restrict__ h_dst,
    const float* __restrict__ W_dst, const float* __restrict__ W_src,
    const float* __restrict__ W_edge, const float* __restrict__ attn_r,
    float* __restrict__ out) {
    __shared__ float Sp[2][DD];
    __shared__ float Fp[2][DD];
    __shared__ float Wp[2][DD];
    __shared__ float S_l[DD];
    __shared__ float fd_l[DD];
    __shared__ float hd_l[IN_DST];
    __shared__ float sZ, sSE, sER;

    int bm = blockIdx.x;
    int b = bm >> 6;
    int m = bm & 63;
    int t = threadIdx.x;
    int lane = t & 63, w = t >> 6;
    int i = t & 127, h = t >> 7;
    (void)b; (void)m;

    if (t < IN_DST) hd_l[t] = h_dst[(size_t)bm * IN_DST + t];

    if (w == 0) {
        float vz = zpart[lane * 512 + bm];     // lane = ti (NTILE==64)
        vz = wave_sum(vz);
        if (lane == 0) sZ = vz;
    } else if (w == 1) {
        float vs = separt[lane * 512 + bm];
        vs = wave_sum(vs);
        if (lane == 0) sSE = vs;
    }

    float ps = 0.f;
    #pragma unroll
    for (int q = 0; q < NTILE / 2; ++q) {
        int ti = h * (NTILE / 2) + q;
        ps += S_part[((size_t)((bm >> 6) * NTILE + ti) * N_MA + (bm & 63)) * DD + i];
    }
    Sp[h][i] = ps;
    __syncthreads();  // hd_l, Sp, stats ready

    if (t < DD) S_l[t] = Sp[0][t] + Sp[1][t];
    float fa = 0.f;
    #pragma unroll 8
    for (int k = h * 32; k < h * 32 + 32; ++k) fa += hd_l[k] * W_dst[k * DD + i];
    Fp[h][i] = fa;
    __syncthreads();  // S_l, Fp ready

    if (t < DD) fd_l[t] = Fp[0][t] + Fp[1][t];
    float acc = 0.f;
    #pragma unroll 8
    for (int q = 0; q < 64; ++q) {
        int ii = h * 64 + q;
        acc += S_l[ii] * W_src[ii * DD + i];
    }
    Wp[h][i] = acc;
    __syncthreads();  // fd_l, Wp ready

    if (w == 0) {
        float e = fd_l[lane] * attn_r[lane] + fd_l[lane + 64] * attn_r[lane + 64];
        e = wave_sum(e);
        if (lane == 0) sER = e;
    }
    __syncthreads();

    if (t < DD) {
        float p_kk = __expf(lrelu(2.f * sER));
        float Z = sZ + p_kk;
        float invZ = 1.f / Z;
        float bsrc = (Wp[0][i] + Wp[1][i]) * invZ;
        float val = W_edge[i] * (sSE * invZ) + bsrc + fd_l[i] * (p_kk * invZ);
        out[(size_t)bm * DD + i] = 1.f / (1.f + __expf(-val));
    }
}

extern "C" void kernel_launch(void* const* d_in, const int* in_sizes, int n_in,
                              void* d_out, int out_size, void* d_ws, size_t ws_size,
                              hipStream_t stream) {
    const float* h_src = (const float*)d_in[0];
    const float* h_dst = (const float*)d_in[1];
    const float* edge_feat = (const float*)d_in[2];
    const int* adj = (const int*)d_in[3];
    const float* W_src = (const float*)d_in[4];
    const float* W_dst = (const float*)d_in[5];
    const float* W_edge = (const float*)d_in[6];
    const float* attn_l = (const float*)d_in[7];
    const float* attn_r = (const float*)d_in[8];
    float* out = (float*)d_out;

    float* ws = (float*)d_ws;
    float* zpart = ws;                       // 64*512 = 32768
    float* separt = ws + 32768;              // 32768
    float* S_part = ws + 65536;              // 8*64*64*128 = 4194304
    float* u_ws = ws + 4259840;              // 128
    float* cwe_ws = ws + 4259968;            // 1
    float* er_ws = ws + 4260096;             // 512
    int* flags = (int*)(ws + 4260864);       // 8

    f_kernel<<<NB * NTILE + NB, 256, 0, stream>>>(
        h_src, h_dst, edge_feat, adj, W_src, W_dst, W_edge, attn_l, attn_r,
        S_part, zpart, separt, u_ws, cwe_ws, er_ws, flags);
    c2_kernel<<<NB * N_MA, 256, 0, stream>>>(
        S_part, zpart, separt, h_dst, W_dst, W_src, W_edge, attn_r, out);
}

// Round 11
// 22.779 us; speedup vs baseline: 2.7525x; 2.7525x over previous
//
#include <hip/hip_runtime.h>
#include <math.h>

#define NB 8
#define N_OP 1000
#define N_MA 64
#define IN_DST 64
#define DD 128
#define NEG_SLOPE 0.2f
#define TILE_O 32
#define NTILE 32   // 32*32 = 1024 >= 1000 (tail guarded)
#define HPAD 132   // H tile stride: breaks bank aliasing on the el reduce

__device__ __forceinline__ float lrelu(float x) { return x >= 0.f ? x : NEG_SLOPE * x; }

__device__ __forceinline__ float wave_sum(float v) {
    for (int off = 32; off; off >>= 1) v += __shfl_xor(v, off, 64);
    return v;
}

// K1: independent precomputes in one launch. (proven R6 kernel)
// blocks [0,33): u[i] = dot(W_src[i,:], attn_l) (one row/wave), blk32.w0 -> c_we
// blocks [33,161): feat_dst row + er (one bm/wave)
__global__ __launch_bounds__(256) void prep_fdst(
    const float* __restrict__ W_src, const float* __restrict__ W_edge,
    const float* __restrict__ attn_l, const float* __restrict__ h_dst,
    const float* __restrict__ W_dst, const float* __restrict__ attn_r,
    float* __restrict__ u, float* __restrict__ c_we,
    float* __restrict__ feat_dst, float* __restrict__ er) {
    int blk = blockIdx.x;
    int lane = threadIdx.x & 63;
    int w = threadIdx.x >> 6;
    if (blk < 33) {
        int task = blk * 4 + w;
        float al0 = attn_l[lane], al1 = attn_l[lane + 64];
        if (task < 128) {
            float part = W_src[task * DD + lane] * al0 +
                         W_src[task * DD + lane + 64] * al1;
            part = wave_sum(part);
            if (lane == 0) u[task] = part;
        } else if (task == 128) {
            float part = W_edge[lane] * al0 + W_edge[lane + 64] * al1;
            part = wave_sum(part);
            if (lane == 0) c_we[0] = part;
        }
    } else {
        int bm = (blk - 33) * 4 + w;     // < 512
        const float* h = h_dst + (size_t)bm * IN_DST;
        float a0 = 0.f, a1 = 0.f;
        #pragma unroll 8
        for (int k = 0; k < IN_DST; ++k) {
            float hk = h[k];
            a0 += hk * W_dst[k * DD + lane];
            a1 += hk * W_dst[k * DD + lane + 64];
        }
        feat_dst[(size_t)bm * DD + lane] = a0;
        feat_dst[(size_t)bm * DD + lane + 64] = a1;
        float r = a0 * attn_r[lane] + a1 * attn_r[lane + 64];
        r = wave_sum(r);
        if (lane == 0) er[bm] = r;
    }
}

// K2: per (b, o-tile), 512 threads (8 waves -> 2 waves/SIMD for latency
// overlap). Stage H; el in-block (16-thread-group reduce from LDS); masked
// exp stats (M=0; logits bounded ~14, safe f32); partial contraction
// S_part[b,ti,m,i] = sum_o p[o,m]*H[o,i].
__global__ __launch_bounds__(512) void ab_kernel(
    const float* __restrict__ edge_feat, const int* __restrict__ adj,
    const float* __restrict__ h_src, const float* __restrict__ u,
    const float* __restrict__ er, const float* __restrict__ c_we_p,
    float* __restrict__ S_part, float* __restrict__ zpart,
    float* __restrict__ separt) {
    __shared__ float H_l[TILE_O][HPAD];    // 16.9 KB
    __shared__ float P_l[TILE_O][N_MA];    // 8 KB
    __shared__ float u_l[DD];
    __shared__ float el_l[TILE_O];
    __shared__ float redz[8][64], redse[8][64];  // 4 KB

    int blk = blockIdx.x;               // 0..255
    int b = blk >> 5, ti = blk & 31;
    int o0 = ti * TILE_O;
    int nrows = min(TILE_O, N_OP - o0); // 32 (8 for ti==31)
    int t = threadIdx.x;                // 0..511

    float cwe = c_we_p[0];

    // stage H tile (coalesced float4); zero OOB rows
    #pragma unroll
    for (int c = 0; c < 2; ++c) {
        int flat = c * 512 + t;          // 1024 float4 slots = 32 rows x 32
        int row = flat >> 5, col = (flat & 31) * 4;
        float4 hv = make_float4(0.f, 0.f, 0.f, 0.f);
        if (row < nrows)
            hv = *reinterpret_cast<const float4*>(
                h_src + ((size_t)(b * N_OP + o0 + row) * DD + col));
        *reinterpret_cast<float4*>(&H_l[row][col]) = hv;
    }
    if (t < DD) u_l[t] = u[t];
    __syncthreads();

    // el[r] = dot(H[r,:], u): 16 threads/row x 8 FMA (OOB rows give 0)
    {
        int r = t >> 4, sub = t & 15;
        float part = 0.f;
        #pragma unroll
        for (int q = 0; q < 8; ++q)
            part += H_l[r][sub + 16 * q] * u_l[sub + 16 * q];
        part += __shfl_xor(part, 1, 64);
        part += __shfl_xor(part, 2, 64);
        part += __shfl_xor(part, 4, 64);
        part += __shfl_xor(part, 8, 64);
        if (sub == 0) el_l[r] = part;
    }
    __syncthreads();

    // phase 1: p + per-tile stats (coalesced adj/ef rows); 8 row-groups
    int m = t & 63, og = t >> 6;        // og in [0,8)
    float er_bm = er[b * N_MA + m];
    float z = 0.f, se = 0.f;
    #pragma unroll
    for (int r = og; r < TILE_O; r += 8) {
        float p = 0.f;
        if (r < nrows) {
            size_t eidx = (size_t)(b * N_OP + o0 + r) * N_MA + m;
            if (adj[eidx]) {
                float efv = edge_feat[eidx];
                float v = lrelu(el_l[r] + er_bm + efv * cwe);
                p = __expf(v);
                z += p;
                se += p * efv;
            }
        }
        P_l[r][m] = p;
    }
    redz[og][m] = z;
    redse[og][m] = se;
    __syncthreads();

    if (t < 64) {
        float s = 0.f;
        #pragma unroll
        for (int g = 0; g < 8; ++g) s += redz[g][t];
        zpart[ti * 512 + b * N_MA + t] = s;
    } else if (t < 128) {
        int mm = t - 64;
        float s = 0.f;
        #pragma unroll
        for (int g = 0; g < 8; ++g) s += redse[g][mm];
        separt[ti * 512 + b * N_MA + mm] = s;
    }

    // phase 2: S_part[m][i] = sum_k P_l[k][m] * H_l[k][i]
    // thread (i4 = t&31, mg = t>>5 in [0,16)): i = i4*4..+3, m = mg*4..+3
    int i4 = t & 31, mg = t >> 5;
    float acc[4][4];
    #pragma unroll
    for (int a = 0; a < 4; ++a)
        #pragma unroll
        for (int c = 0; c < 4; ++c) acc[a][c] = 0.f;

    for (int k = 0; k < TILE_O; ++k) {
        float4 hv = *reinterpret_cast<const float4*>(&H_l[k][i4 * 4]);
        float4 pa = *reinterpret_cast<const float4*>(&P_l[k][mg * 4]);
        float hh[4] = {hv.x, hv.y, hv.z, hv.w};
        float pp[4] = {pa.x, pa.y, pa.z, pa.w};
        #pragma unroll
        for (int mm = 0; mm < 4; ++mm)
            #pragma unroll
            for (int ii = 0; ii < 4; ++ii)
                acc[mm][ii] += pp[mm] * hh[ii];
    }

    #pragma unroll
    for (int mm = 0; mm < 4; ++mm) {
        size_t off = ((size_t)(b * NTILE + ti) * N_MA + mg * 4 + mm) * DD + i4 * 4;
        *reinterpret_cast<float4*>(S_part + off) =
            make_float4(acc[mm][0], acc[mm][1], acc[mm][2], acc[mm][3]);
    }
}

// K3: per (b,m): sum partials, matvec with W_src, epilogue sigmoid.
// (proven R6 kernel)
__global__ __launch_bounds__(256) void c_kernel(
    const float* __restrict__ S_part, const float* __restrict__ zpart,
    const float* __restrict__ separt, const float* __restrict__ er,
    const float* __restrict__ feat_dst, const float* __restrict__ W_src,
    const float* __restrict__ W_edge, float* __restrict__ out) {
    __shared__ float Sp[2][DD];
    __shared__ float S_l[DD];
    __shared__ float Wp[2][DD];
    __shared__ float sZ, sSE;

    int bm = blockIdx.x;
    int b = bm >> 6, m = bm & 63;
    int t = threadIdx.x;
    int i = t & 127, h = t >> 7;
    int lane = t & 63, w = t >> 6;

    if (w == 0) {
        float v = (lane < NTILE) ? zpart[lane * 512 + bm] : 0.f;
        v = wave_sum(v);
        if (lane == 0) sZ = v;
    } else if (w == 1) {
        float v = (lane < NTILE) ? separt[lane * 512 + bm] : 0.f;
        v = wave_sum(v);
        if (lane == 0) sSE = v;
    }

    float ps = 0.f;
    #pragma unroll
    for (int q = 0; q < NTILE / 2; ++q) {
        int ti = h * (NTILE / 2) + q;
        ps += S_part[((size_t)(b * NTILE + ti) * N_MA + m) * DD + i];
    }
    Sp[h][i] = ps;
    __syncthreads();
    if (t < DD) S_l[t] = Sp[0][t] + Sp[1][t];
    __syncthreads();

    float acc = 0.f;
    #pragma unroll 8
    for (int q = 0; q < 64; ++q) {
        int ii = h * 64 + q;
        acc += S_l[ii] * W_src[ii * DD + i];
    }
    Wp[h][i] = acc;
    __syncthreads();

    if (t < DD) {
        float er_bm = er[bm];
        float p_kk = __expf(lrelu(2.f * er_bm));
        float Z = sZ + p_kk;
        float invZ = 1.f / Z;
        float bsrc = (Wp[0][i] + Wp[1][i]) * invZ;
        float val = W_edge[i] * (sSE * invZ) + bsrc +
                    feat_dst[(size_t)bm * DD + i] * (p_kk * invZ);
        out[(size_t)bm * DD + i] = 1.f / (1.f + __expf(-val));
    }
}

extern "C" void kernel_launch(void* const* d_in, const int* in_sizes, int n_in,
                              void* d_out, int out_size, void* d_ws, size_t ws_size,
                              hipStream_t stream) {
    const float* h_src = (const float*)d_in[0];
    const float* h_dst = (const float*)d_in[1];
    const float* edge_feat = (const float*)d_in[2];
    const int* adj = (const int*)d_in[3];
    const float* W_src = (const float*)d_in[4];
    const float* W_dst = (const float*)d_in[5];
    const float* W_edge = (const float*)d_in[6];
    const float* attn_l = (const float*)d_in[7];
    const float* attn_r = (const float*)d_in[8];
    float* out = (float*)d_out;

    float* ws = (float*)d_ws;
    float* u = ws;                     // 128
    float* c_we = ws + 128;            // 1
    float* er = ws + 8448;             // 512
    float* feat_dst = ws + 9216;       // 65536
    float* zpart = ws + 75008;         // 32*512 = 16384
    float* separt = ws + 91392;        // 16384
    float* S_part = ws + 107776;       // 8*32*64*128 = 2097152

    prep_fdst<<<161, 256, 0, stream>>>(W_src, W_edge, attn_l, h_dst, W_dst,
                                       attn_r, u, c_we, feat_dst, er);
    ab_kernel<<<NB * NTILE, 512, 0, stream>>>(edge_feat, adj, h_src, u, er,
                                              c_we, S_part, zpart, separt);
    c_kernel<<<NB * N_MA, 256, 0, stream>>>(S_part, zpart, separt, er,
                                            feat_dst, W_src, W_edge, out);
}